// Round 16
// baseline (70.262 us; speedup 1.0000x reference)
//
#include <hip/hip_runtime.h>
#include <math.h>

// ProxyNCA loss, MFMA version — round 16.
// logit_ic = 18 * xhat_i . phat_c ;  nll_i = log(sum_c exp(logit_ic)) - logit_{i,T_i}
// Both operands prescaled by sqrt(18*log2(e)) = 5.0959308 into bf16; the MFMA
// accumulator holds log2(e)*logit, so exp = v_exp_f32 directly.
//
// Round 16 vs round 15: switch 16x16x32 -> 32x32x16 MFMA.
// R15 closed the occupancy question: (512,4) == (512,2) exactly (51us, VGPR
// 52, occ 30%) — residency is pinned at ~2.4 waves/SIMD by the unified
// register footprint; hints and grid size don't move it. At fixed
// concurrency, duration = 2x total vector work (VALU busy 25.5us of 51).
// So cut the work: 32x32x16 does the same FLOPs in HALF the MFMA instrs
// (1.05M vs 2.1M), at a 15% higher ceiling (2382 vs 2075 TF), with 16
// exp-ready outputs per chain and HALF the epilogue (1 shfl + 1 store per
// 32 rows; psum single-f32). Layouts per verified m74/m101 mapping:
//   C/D: col = lane&31, row(class) = (reg&3) + 8*(reg>>2) + 4*(lane>>5)
//   A/B: lane = idx&31 + 32*khalf, 8 contiguous k-elems (K=16 = 2x8).
// Everything else: P-in-LDS via global_load_lds (R13), CBLK=128, RSPLIT=2,
// 2-tile ILP, (512,2) (spill ledger: only config that never spilled).

#define NROWS 4096
#define NCLS  65536
#define DIM   64
#define CBLK  128                 // classes per block
#define NBLK  (NCLS / CBLK)       // 512 class-blocks
#define RSPLIT 2                  // row halves -> grid 1024
#define NCH   (CBLK / 32)         // 4 chunks of 32 classes
#define NPB   (NCLS / 4)          // prep blocks for P (4 rows each)

typedef __attribute__((ext_vector_type(8)))  short short8;
typedef __attribute__((ext_vector_type(16))) float f32x16;

#define PRESCALE 5.0959308f       // sqrt(18 * log2(e))

__device__ __forceinline__ short bf16rne(float f) {
    union { float f; unsigned u; } v; v.f = f;
    unsigned r = (v.u + 0x7fffu + ((v.u >> 16) & 1u)) >> 16;
    return (short)r;
}

// ---- fused prep: blocks [0,NPB) pack P -> Pb; blocks [NPB,..) do X/st ----
// Pb ushort index for (class row, dim d), 32-class chunks, K=16 slices:
//   chunk32 = row>>5, slice = d>>4, khalf = (d>>3)&1, elem = d&7
//   lane = (row&31) + 32*khalf
//   idx = chunk32*2048 + slice*512 + lane*8 + elem
// Class-block b = chunk32 4b..4b+3 = 16KB contiguous at byte offset b*16384.
__global__ void k_prep(const float* __restrict__ X, const float* __restrict__ P,
                       const int* __restrict__ T,
                       unsigned short* __restrict__ Pb,
                       unsigned short* __restrict__ Xb, float* __restrict__ st,
                       float* __restrict__ out) {
    int bx = blockIdx.x;
    int t  = threadIdx.x;
    if (bx < NPB) {
        int row = bx * 4 + (t >> 6);
        int d   = t & 63;
        float v  = P[row * DIM + d];
        float sq = v * v;
        #pragma unroll
        for (int off = 32; off > 0; off >>= 1) sq += __shfl_xor(sq, off);
        float sc = PRESCALE * rsqrtf(fmaxf(sq, 1e-24f));
        int idx = (row >> 5) * 2048 + (d >> 4) * 512
                + ((row & 31) + 32 * ((d >> 3) & 1)) * 8 + (d & 7);
        Pb[idx] = (unsigned short)bf16rne(v * sc);
    } else {
        if (bx == NPB && t == 0) out[0] = 0.0f;
        int row  = (bx - NPB) * 4 + (t >> 6);
        int lane = t & 63;
        int tc   = T[row];
        float xv = X[row * DIM + lane];
        float pv = P[tc  * DIM + lane];
        float x2 = xv * xv, p2 = pv * pv, xp = xv * pv;
        #pragma unroll
        for (int off = 32; off > 0; off >>= 1) {
            x2 += __shfl_xor(x2, off);
            p2 += __shfl_xor(p2, off);
            xp += __shfl_xor(xp, off);
        }
        float rx = rsqrtf(fmaxf(x2, 1e-24f));
        Xb[row * DIM + lane] = (unsigned short)bf16rne(xv * (PRESCALE * rx));
        if (lane == 0)
            st[row] = 18.0f * xp * rx * rsqrtf(fmaxf(p2, 1e-24f));
    }
}

// ---- main: block (b,h): classes [b*128,+128) x rows [h*2048,+2048) -------
// P tile (16KB) staged once into LDS; 8 waves; wave w, iter it handles two
// 32-row tiles: rowA = h*2048 + it*512 + w*32, rowB = rowA + 256.
// Per chunk (32 classes): 4 chained mfma_32x32x16 (K=64), then 16 exps.
// D: class = (reg&3)+8*(reg>>2)+4*(lane>>5), xrow = lane&31. Lane's 16 regs
// cover 16 classes (its k-half set); shfl_xor(32) completes all 32.
__global__ __launch_bounds__(512, 2)
void k_main(const unsigned short* __restrict__ Pbu, const unsigned short* __restrict__ Xb,
            float* __restrict__ psum) {
    __shared__ __align__(16) unsigned short plds[NCH * 2048];   // 16 KB

    int t = threadIdx.x;
    int w = t >> 6;
    int l = t & 63;
    int bx = blockIdx.x;
    int b  = bx & (NBLK - 1);
    int h  = bx >> 9;
    int lc = l & 31;              // class-in-chunk (A) / x-row (B)
    int lk = l >> 5;              // k-half

    // ---- stage P tile: 16KB linear copy (identity layout), 2 calls/wave
    {
        const char* src = reinterpret_cast<const char*>(Pbu)
                        + (size_t)b * 16384 + w * 1024 + l * 16;
        __builtin_amdgcn_global_load_lds(
            (const __attribute__((address_space(1))) unsigned int*)src,
            (__attribute__((address_space(3))) unsigned int*)((char*)plds + w * 1024),
            16, 0, 0);
        __builtin_amdgcn_global_load_lds(
            (const __attribute__((address_space(1))) unsigned int*)(src + 8192),
            (__attribute__((address_space(3))) unsigned int*)((char*)plds + 8192 + w * 1024),
            16, 0, 0);
    }
    __syncthreads();              // compiler drains vmcnt before barrier

    const f32x16 zero = {0.0f, 0.0f, 0.0f, 0.0f, 0.0f, 0.0f, 0.0f, 0.0f,
                         0.0f, 0.0f, 0.0f, 0.0f, 0.0f, 0.0f, 0.0f, 0.0f};

    // ---- row sweep: 4 iterations x 2 independent 32-row tiles
    // lane l reads x-row rowbase + lc, k-slice s at ushort s*16 + lk*8.
    const unsigned short* xb = Xb + (size_t)(h * 2048 + w * 32 + lc) * DIM + lk * 8;
    float* prow = psum + (size_t)b * NROWS + h * 2048 + w * 32 + lc;  // lanes<32
    const char* plbase = (const char*)plds + l * 16;

    #pragma unroll 1
    for (int it = 0; it < 4; ++it) {
        short8 xA0 = *reinterpret_cast<const short8*>(xb);
        short8 xA1 = *reinterpret_cast<const short8*>(xb + 16);
        short8 xA2 = *reinterpret_cast<const short8*>(xb + 32);
        short8 xA3 = *reinterpret_cast<const short8*>(xb + 48);
        short8 xB0 = *reinterpret_cast<const short8*>(xb + 16384);       // +256 rows
        short8 xB1 = *reinterpret_cast<const short8*>(xb + 16384 + 16);
        short8 xB2 = *reinterpret_cast<const short8*>(xb + 16384 + 32);
        short8 xB3 = *reinterpret_cast<const short8*>(xb + 16384 + 48);

        float eA0 = 0.f, eA1 = 0.f, eA2 = 0.f, eA3 = 0.f;
        float eB0 = 0.f, eB1 = 0.f, eB2 = 0.f, eB3 = 0.f;
        #pragma unroll
        for (int cc = 0; cc < NCH; ++cc) {
            const char* pc = plbase + cc * 4096;
            short8 p0 = *reinterpret_cast<const short8*>(pc);
            short8 p1 = *reinterpret_cast<const short8*>(pc + 1024);
            short8 p2 = *reinterpret_cast<const short8*>(pc + 2048);
            short8 p3 = *reinterpret_cast<const short8*>(pc + 3072);

            f32x16 cA = __builtin_amdgcn_mfma_f32_32x32x16_bf16(p0, xA0, zero, 0, 0, 0);
            cA = __builtin_amdgcn_mfma_f32_32x32x16_bf16(p1, xA1, cA, 0, 0, 0);
            cA = __builtin_amdgcn_mfma_f32_32x32x16_bf16(p2, xA2, cA, 0, 0, 0);
            cA = __builtin_amdgcn_mfma_f32_32x32x16_bf16(p3, xA3, cA, 0, 0, 0);
            f32x16 cB = __builtin_amdgcn_mfma_f32_32x32x16_bf16(p0, xB0, zero, 0, 0, 0);
            cB = __builtin_amdgcn_mfma_f32_32x32x16_bf16(p1, xB1, cB, 0, 0, 0);
            cB = __builtin_amdgcn_mfma_f32_32x32x16_bf16(p2, xB2, cB, 0, 0, 0);
            cB = __builtin_amdgcn_mfma_f32_32x32x16_bf16(p3, xB3, cB, 0, 0, 0);

            #pragma unroll
            for (int j = 0; j < 4; ++j) {
                float a = __builtin_amdgcn_exp2f(cA[j])
                        + __builtin_amdgcn_exp2f(cA[j + 4])
                        + __builtin_amdgcn_exp2f(cA[j + 8])
                        + __builtin_amdgcn_exp2f(cA[j + 12]);
                float bb = __builtin_amdgcn_exp2f(cB[j])
                         + __builtin_amdgcn_exp2f(cB[j + 4])
                         + __builtin_amdgcn_exp2f(cB[j + 8])
                         + __builtin_amdgcn_exp2f(cB[j + 12]);
                if (j == 0)      { eA0 += a; eB0 += bb; }
                else if (j == 1) { eA1 += a; eB1 += bb; }
                else if (j == 2) { eA2 += a; eB2 += bb; }
                else             { eA3 += a; eB3 += bb; }
            }
        }
        float sA = (eA0 + eA1) + (eA2 + eA3);
        float sB = (eB0 + eB1) + (eB2 + eB3);
        sA += __shfl_xor(sA, 32);     // add the other k-half's 16 classes
        sB += __shfl_xor(sB, 32);
        if (l < 32) {
            prow[0]   = sA;           // rows h*2048 + it*512 + w*32 + lc
            prow[256] = sB;           // +256 rows
        }

        xb   += 512 * DIM;            // +512 rows
        prow += 512;
    }
}

// ---- per-row finish + global mean, 256 blocks x 16 rows ------------------
// thread t: j = t>>4 sums block-range [j*32, +32); ri = t&15 = row in block.
__global__ void k_rowred(const float* __restrict__ psum, const float* __restrict__ st,
                         float* __restrict__ out) {
    __shared__ float red[256];
    __shared__ float rnll[16];
    int t  = threadIdx.x;
    int j  = t >> 4;
    int ri = t & 15;
    int r  = blockIdx.x * 16 + ri;
    float s = 0.0f;
    #pragma unroll 4
    for (int i = j * 32; i < j * 32 + 32; ++i)
        s += psum[(size_t)i * NROWS + r];
    red[t] = s;
    __syncthreads();
    if (t < 128) red[t] += red[t + 128];
    __syncthreads();
    if (t < 64)  red[t] += red[t + 64];
    __syncthreads();
    if (t < 32)  red[t] += red[t + 32];
    __syncthreads();
    if (t < 16) {
        float tot = red[t] + red[t + 16];
        rnll[t] = logf(tot) - st[r];
    }
    __syncthreads();
    if (t == 0) {
        float a = 0.0f;
        #pragma unroll
        for (int k = 0; k < 16; ++k) a += rnll[k];
        atomicAdd(out, a * (1.0f / (float)NROWS));
    }
}

extern "C" void kernel_launch(void* const* d_in, const int* in_sizes, int n_in,
                              void* d_out, int out_size, void* d_ws, size_t ws_size,
                              hipStream_t stream) {
    const float* X = (const float*)d_in[0];
    const float* P = (const float*)d_in[1];
    const int*   T = (const int*)  d_in[3];   // d_in[2] = indices (unused)
    float* out = (float*)d_out;

    char* ws = (char*)d_ws;
    unsigned short* Xb = (unsigned short*)ws;                 // 512 KB
    float* st   = (float*)(ws + (512 << 10));                 // 16 KB
    unsigned short* Pb = (unsigned short*)(ws + (576 << 10)); // 8 MB (packed frags)
    float* psum = (float*)(ws + (9 << 20));                   // 8 MB (512 x 4096 f32)

    k_prep  <<<NPB + NROWS / 4, 256, 0, stream>>>(X, P, T, Pb, Xb, st, out);
    k_main  <<<NBLK * RSPLIT, 512, 0, stream>>>(Pb, Xb, psum);
    k_rowred<<<256, 256, 0, stream>>>(psum, st, out);
}

// Round 17
// 67.285 us; speedup vs baseline: 1.0442x; 1.0442x over previous
//
#include <hip/hip_runtime.h>
#include <math.h>

// ProxyNCA loss, MFMA version — round 17.
// logit_ic = 18 * xhat_i . phat_c ;  nll_i = log(sum_c exp(logit_ic)) - logit_{i,T_i}
// Both operands prescaled by sqrt(18*log2(e)) = 5.0959308 into bf16; the
// 16x16x32 bf16 MFMA accumulator holds log2(e)*logit, so exp = v_exp_f32.
//
// Round 17 vs rounds 13/15/16: halve LDS traffic at constant structure.
// R16 (32x32) regressed: f32x16 accs = 32 AGPRs -> VGPR 92 -> occupancy 15%
// -> 58us. Law of the session: duration ~ resident waves x per-wave critical
// path; instr savings that cost registers lose. Back to 16x16 (R13/R15).
// Corrected pipe audit of R15: LDS pipe ~20.4us/CU is the largest shared
// demand (each wave re-reads the 16KB P tile per 32-row iter). This round:
// 4 row-tiles (64 rows) per iter -> per-wave LDS reads 128KB -> 64KB
// (LDS demand ~10us), iters and epilogue halve. +16 X regs + 8 exp chains
// (~70 arch + 16 acc), inside the (512,2) no-spill envelope (<=92 ledger).
// Everything else identical to R13: P-in-LDS via global_load_lds, CBLK=128,
// RSPLIT=2, single-shfl epilogue, [row][2]-partial psum, 256-block rowred.

#define NROWS 4096
#define NCLS  65536
#define DIM   64
#define CBLK  128                 // classes per block
#define NBLK  (NCLS / CBLK)       // 512 class-blocks
#define RSPLIT 2                  // row halves -> grid 1024
#define NCH   (CBLK / 16)         // 8 MFMA chunks of 16 classes
#define NPB   (NCLS / 4)          // prep blocks for P (4 rows each)

typedef __attribute__((ext_vector_type(8))) short short8;
typedef __attribute__((ext_vector_type(4))) float f32x4;

#define PRESCALE 5.0959308f       // sqrt(18 * log2(e))

__device__ __forceinline__ short bf16rne(float f) {
    union { float f; unsigned u; } v; v.f = f;
    unsigned r = (v.u + 0x7fffu + ((v.u >> 16) & 1u)) >> 16;
    return (short)r;
}

// ---- fused prep: blocks [0,NPB) pack P -> Pb; blocks [NPB,..) do X/st ----
// Pb ushort index for (class row, dim d):
//   chunk=row>>4, half=d>>5, lane=(row&15)+16*((d>>3)&3), elem=d&7
//   idx = chunk*1024 + half*512 + lane*8 + elem
// Class-block b = chunks 8b..8b+7 = 16KB contiguous at byte offset b*16384.
__global__ void k_prep(const float* __restrict__ X, const float* __restrict__ P,
                       const int* __restrict__ T,
                       unsigned short* __restrict__ Pb,
                       unsigned short* __restrict__ Xb, float* __restrict__ st,
                       float* __restrict__ out) {
    int bx = blockIdx.x;
    int t  = threadIdx.x;
    if (bx < NPB) {
        int row = bx * 4 + (t >> 6);
        int d   = t & 63;
        float v  = P[row * DIM + d];
        float sq = v * v;
        #pragma unroll
        for (int off = 32; off > 0; off >>= 1) sq += __shfl_xor(sq, off);
        float sc = PRESCALE * rsqrtf(fmaxf(sq, 1e-24f));
        int idx = (row >> 4) * 1024 + (d >> 5) * 512
                + ((row & 15) + ((d >> 3) & 3) * 16) * 8 + (d & 7);
        Pb[idx] = (unsigned short)bf16rne(v * sc);
    } else {
        if (bx == NPB && t == 0) out[0] = 0.0f;
        int row  = (bx - NPB) * 4 + (t >> 6);
        int lane = t & 63;
        int tc   = T[row];
        float xv = X[row * DIM + lane];
        float pv = P[tc  * DIM + lane];
        float x2 = xv * xv, p2 = pv * pv, xp = xv * pv;
        #pragma unroll
        for (int off = 32; off > 0; off >>= 1) {
            x2 += __shfl_xor(x2, off);
            p2 += __shfl_xor(p2, off);
            xp += __shfl_xor(xp, off);
        }
        float rx = rsqrtf(fmaxf(x2, 1e-24f));
        Xb[row * DIM + lane] = (unsigned short)bf16rne(xv * (PRESCALE * rx));
        if (lane == 0)
            st[row] = 18.0f * xp * rx * rsqrtf(fmaxf(p2, 1e-24f));
    }
}

// ---- main: block (b,h): classes [b*128,+128) x rows [h*2048,+2048) -------
// P tile (16KB) staged once into LDS. 8 waves; wave w owns rows
// [h*2048 + w*256, +256), swept in 4 iters of 64 rows (4 MFMA row-tiles).
// Per chunk: 2 ds_read_b128 + 8 MFMA (4 tiles x K=64) -> 2x the MFMA work
// per LDS byte vs R15. mfma(P_frag, X_frag): C col = lane&15 = x-row.
// Epilogue per tile: one shfl_xor(32); lanes<32 store 2 partials/row.
__global__ __launch_bounds__(512, 2)
void k_main(const unsigned short* __restrict__ Pbu, const unsigned short* __restrict__ Xb,
            float* __restrict__ psum) {
    __shared__ __align__(16) unsigned short plds[NCH * 2 * 512];   // 16 KB

    int t = threadIdx.x;
    int w = t >> 6;
    int l = t & 63;
    int bx = blockIdx.x;
    int b  = bx & (NBLK - 1);
    int h  = bx >> 9;
    int lm = l & 15;              // x-row within tile
    int lk = l >> 4;              // k-group

    // ---- stage P tile: 16KB linear copy (identity layout), 2 calls/wave
    {
        const char* src = reinterpret_cast<const char*>(Pbu)
                        + (size_t)b * 16384 + w * 1024 + l * 16;
        __builtin_amdgcn_global_load_lds(
            (const __attribute__((address_space(1))) unsigned int*)src,
            (__attribute__((address_space(3))) unsigned int*)((char*)plds + w * 1024),
            16, 0, 0);
        __builtin_amdgcn_global_load_lds(
            (const __attribute__((address_space(1))) unsigned int*)(src + 8192),
            (__attribute__((address_space(3))) unsigned int*)((char*)plds + 8192 + w * 1024),
            16, 0, 0);
    }
    __syncthreads();              // compiler drains vmcnt before barrier

    const f32x4 zero = {0.0f, 0.0f, 0.0f, 0.0f};

    // ---- row sweep: 4 iterations x 4 row-tiles (64 rows/iter)
    // row stride: 1 row = 8 short8; 16 rows = 128 short8; 64 rows = 512.
    const short8* xp = reinterpret_cast<const short8*>(
        Xb + (size_t)(h * 2048 + w * 256 + lm) * DIM + lk * 8);
    // psum layout: [block][row][2] f32; lanes l<32 store part lk.
    float* prow = psum + ((size_t)b * NROWS + h * 2048 + w * 256 + lm) * 2 + lk;
    const char* pl = (const char*)plds + l * 16;

    #pragma unroll 1
    for (int it = 0; it < 4; ++it) {
        short8 x0a = xp[0],   x0b = xp[4];      // rows +0..15, k-halves
        short8 x1a = xp[128], x1b = xp[132];    // +16 rows
        short8 x2a = xp[256], x2b = xp[260];    // +32 rows
        short8 x3a = xp[384], x3b = xp[388];    // +48 rows

        float e00 = 0.f, e01 = 0.f, e02 = 0.f, e03 = 0.f;
        float e10 = 0.f, e11 = 0.f, e12 = 0.f, e13 = 0.f;
        float e20 = 0.f, e21 = 0.f, e22 = 0.f, e23 = 0.f;
        float e30 = 0.f, e31 = 0.f, e32 = 0.f, e33 = 0.f;
        #pragma unroll
        for (int ch = 0; ch < NCH; ++ch) {
            short8 p0 = *reinterpret_cast<const short8*>(pl + ch * 2048);
            short8 p1 = *reinterpret_cast<const short8*>(pl + ch * 2048 + 1024);
            f32x4 c0 = __builtin_amdgcn_mfma_f32_16x16x32_bf16(p0, x0a, zero, 0, 0, 0);
            c0 = __builtin_amdgcn_mfma_f32_16x16x32_bf16(p1, x0b, c0, 0, 0, 0);
            f32x4 c1 = __builtin_amdgcn_mfma_f32_16x16x32_bf16(p0, x1a, zero, 0, 0, 0);
            c1 = __builtin_amdgcn_mfma_f32_16x16x32_bf16(p1, x1b, c1, 0, 0, 0);
            f32x4 c2 = __builtin_amdgcn_mfma_f32_16x16x32_bf16(p0, x2a, zero, 0, 0, 0);
            c2 = __builtin_amdgcn_mfma_f32_16x16x32_bf16(p1, x2b, c2, 0, 0, 0);
            f32x4 c3 = __builtin_amdgcn_mfma_f32_16x16x32_bf16(p0, x3a, zero, 0, 0, 0);
            c3 = __builtin_amdgcn_mfma_f32_16x16x32_bf16(p1, x3b, c3, 0, 0, 0);
            e00 += __builtin_amdgcn_exp2f(c0[0]);
            e01 += __builtin_amdgcn_exp2f(c0[1]);
            e02 += __builtin_amdgcn_exp2f(c0[2]);
            e03 += __builtin_amdgcn_exp2f(c0[3]);
            e10 += __builtin_amdgcn_exp2f(c1[0]);
            e11 += __builtin_amdgcn_exp2f(c1[1]);
            e12 += __builtin_amdgcn_exp2f(c1[2]);
            e13 += __builtin_amdgcn_exp2f(c1[3]);
            e20 += __builtin_amdgcn_exp2f(c2[0]);
            e21 += __builtin_amdgcn_exp2f(c2[1]);
            e22 += __builtin_amdgcn_exp2f(c2[2]);
            e23 += __builtin_amdgcn_exp2f(c2[3]);
            e30 += __builtin_amdgcn_exp2f(c3[0]);
            e31 += __builtin_amdgcn_exp2f(c3[1]);
            e32 += __builtin_amdgcn_exp2f(c3[2]);
            e33 += __builtin_amdgcn_exp2f(c3[3]);
        }
        float s0 = (e00 + e01) + (e02 + e03);
        float s1 = (e10 + e11) + (e12 + e13);
        float s2 = (e20 + e21) + (e22 + e23);
        float s3 = (e30 + e31) + (e32 + e33);
        s0 += __shfl_xor(s0, 32);     // lane partial over {lk, lk^2}
        s1 += __shfl_xor(s1, 32);
        s2 += __shfl_xor(s2, 32);
        s3 += __shfl_xor(s3, 32);
        if (l < 32) {
            prow[0]      = s0;        // rows base + it*64 + 0..15
            prow[16 * 2] = s1;        // +16 rows
            prow[32 * 2] = s2;        // +32 rows
            prow[48 * 2] = s3;        // +48 rows
        }

        xp   += 512;                  // +64 rows
        prow += 64 * 2;
    }
}

// ---- per-row finish + global mean, 256 blocks x 16 rows ------------------
// thread t: j = t>>4 sums block-range [j*32, +32); ri = t&15 = row in block.
__global__ void k_rowred(const float* __restrict__ psum, const float* __restrict__ st,
                         float* __restrict__ out) {
    __shared__ float red[256];
    __shared__ float rnll[16];
    int t  = threadIdx.x;
    int j  = t >> 4;
    int ri = t & 15;
    int r  = blockIdx.x * 16 + ri;
    const float2* p2 = reinterpret_cast<const float2*>(psum) + r;
    float s = 0.0f;
    #pragma unroll 4
    for (int i = j * 32; i < j * 32 + 32; ++i) {
        float2 v = p2[(size_t)i * NROWS];
        s += v.x + v.y;
    }
    red[t] = s;
    __syncthreads();
    if (t < 128) red[t] += red[t + 128];
    __syncthreads();
    if (t < 64)  red[t] += red[t + 64];
    __syncthreads();
    if (t < 32)  red[t] += red[t + 32];
    __syncthreads();
    if (t < 16) {
        float tot = red[t] + red[t + 16];
        rnll[t] = logf(tot) - st[r];
    }
    __syncthreads();
    if (t == 0) {
        float a = 0.0f;
        #pragma unroll
        for (int k = 0; k < 16; ++k) a += rnll[k];
        atomicAdd(out, a * (1.0f / (float)NROWS));
    }
}

extern "C" void kernel_launch(void* const* d_in, const int* in_sizes, int n_in,
                              void* d_out, int out_size, void* d_ws, size_t ws_size,
                              hipStream_t stream) {
    const float* X = (const float*)d_in[0];
    const float* P = (const float*)d_in[1];
    const int*   T = (const int*)  d_in[3];   // d_in[2] = indices (unused)
    float* out = (float*)d_out;

    char* ws = (char*)d_ws;
    unsigned short* Xb = (unsigned short*)ws;                 // 512 KB
    float* st   = (float*)(ws + (512 << 10));                 // 16 KB
    unsigned short* Pb = (unsigned short*)(ws + (576 << 10)); // 8 MB (packed frags)
    float* psum = (float*)(ws + (9 << 20));                   // 16 MB (512 x 4096 x 2)

    k_prep  <<<NPB + NROWS / 4, 256, 0, stream>>>(X, P, T, Pb, Xb, st, out);
    k_main  <<<NBLK * RSPLIT, 512, 0, stream>>>(Pb, Xb, psum);
    k_rowred<<<256, 256, 0, stream>>>(psum, st, out);
}

// Round 18
// 64.512 us; speedup vs baseline: 1.0891x; 1.0430x over previous
//
#include <hip/hip_runtime.h>
#include <math.h>

// ProxyNCA loss, MFMA version — round 18 (= round 13 verbatim, the measured
// session best: 64.3us total, k_main 49.0us).
// logit_ic = 18 * xhat_i . phat_c ;  nll_i = log(sum_c exp(logit_ic)) - logit_{i,T_i}
// Both operands prescaled by sqrt(18*log2(e)) = 5.0959308 into bf16; the
// 16x16x32 bf16 MFMA accumulator holds log2(e)*logit, so exp = v_exp_f32.
//
// Lever matrix closed over R8-R17 (all null or negative at this plateau):
// ILP 2/4-tile, grid x2/x4, hints (512,{2,4,8}), P-in-regs vs P-in-LDS,
// 32x32 MFMA, LDS-traffic halving. Structural constraint: MFMA->exp->acc
// join latency at the ~2-4 effective waves/SIMD this footprint permits;
// summed pipe busy ~= duration/2 in every config. Floor max(MFMA 13.7,
// LDS ~10-20, VALU ~12us) vs 49 measured — residual is dependency stall,
// and both scheduling-control candidates (T19/T5) are null-as-graft.
// This round: pure revert to the best measured configuration.

#define NROWS 4096
#define NCLS  65536
#define DIM   64
#define CBLK  128                 // classes per block
#define NBLK  (NCLS / CBLK)       // 512 class-blocks
#define RSPLIT 2                  // row halves -> grid 1024
#define NCH   (CBLK / 16)         // 8 MFMA chunks of 16 classes
#define NPB   (NCLS / 4)          // prep blocks for P (4 rows each)

typedef __attribute__((ext_vector_type(8))) short short8;
typedef __attribute__((ext_vector_type(4))) float f32x4;

#define PRESCALE 5.0959308f       // sqrt(18 * log2(e))

__device__ __forceinline__ short bf16rne(float f) {
    union { float f; unsigned u; } v; v.f = f;
    unsigned r = (v.u + 0x7fffu + ((v.u >> 16) & 1u)) >> 16;
    return (short)r;
}

// ---- fused prep: blocks [0,NPB) pack P -> Pb; blocks [NPB,..) do X/st ----
// Pb ushort index for (class row, dim d):
//   chunk=row>>4, half=d>>5, lane=(row&15)+16*((d>>3)&3), elem=d&7
//   idx = chunk*1024 + half*512 + lane*8 + elem
// Class-block b = chunks 8b..8b+7 = 16KB contiguous at byte offset b*16384.
__global__ void k_prep(const float* __restrict__ X, const float* __restrict__ P,
                       const int* __restrict__ T,
                       unsigned short* __restrict__ Pb,
                       unsigned short* __restrict__ Xb, float* __restrict__ st,
                       float* __restrict__ out) {
    int bx = blockIdx.x;
    int t  = threadIdx.x;
    if (bx < NPB) {
        int row = bx * 4 + (t >> 6);
        int d   = t & 63;
        float v  = P[row * DIM + d];
        float sq = v * v;
        #pragma unroll
        for (int off = 32; off > 0; off >>= 1) sq += __shfl_xor(sq, off);
        float sc = PRESCALE * rsqrtf(fmaxf(sq, 1e-24f));
        int idx = (row >> 4) * 1024 + (d >> 5) * 512
                + ((row & 15) + ((d >> 3) & 3) * 16) * 8 + (d & 7);
        Pb[idx] = (unsigned short)bf16rne(v * sc);
    } else {
        if (bx == NPB && t == 0) out[0] = 0.0f;
        int row  = (bx - NPB) * 4 + (t >> 6);
        int lane = t & 63;
        int tc   = T[row];
        float xv = X[row * DIM + lane];
        float pv = P[tc  * DIM + lane];
        float x2 = xv * xv, p2 = pv * pv, xp = xv * pv;
        #pragma unroll
        for (int off = 32; off > 0; off >>= 1) {
            x2 += __shfl_xor(x2, off);
            p2 += __shfl_xor(p2, off);
            xp += __shfl_xor(xp, off);
        }
        float rx = rsqrtf(fmaxf(x2, 1e-24f));
        Xb[row * DIM + lane] = (unsigned short)bf16rne(xv * (PRESCALE * rx));
        if (lane == 0)
            st[row] = 18.0f * xp * rx * rsqrtf(fmaxf(p2, 1e-24f));
    }
}

// ---- main: block (b,h): classes [b*128,+128) x rows [h*2048,+2048) -------
// P tile (16KB) staged once into LDS; frags re-read per chunk (ds_read_b128,
// lane-contiguous -> conflict-free). 8 waves; wave w, iter it handles
// row-tiles at rows h*2048 + 256*it + w*16 (+128 for B tile).
// mfma(P_frag, X_frag): C col = lane&15 = x-row, regs = 4 classes.
__global__ __launch_bounds__(512, 2)
void k_main(const unsigned short* __restrict__ Pbu, const unsigned short* __restrict__ Xb,
            float* __restrict__ psum) {
    __shared__ __align__(16) unsigned short plds[NCH * 2 * 512];   // 16 KB

    int t = threadIdx.x;
    int w = t >> 6;
    int l = t & 63;
    int bx = blockIdx.x;
    int b  = bx & (NBLK - 1);
    int h  = bx >> 9;
    int lm = l & 15;              // x-row within tile
    int lk = l >> 4;              // k-group

    // ---- stage P tile: 16KB linear copy (identity layout), 2 calls/wave
    {
        const char* src = reinterpret_cast<const char*>(Pbu)
                        + (size_t)b * 16384 + w * 1024 + l * 16;
        __builtin_amdgcn_global_load_lds(
            (const __attribute__((address_space(1))) unsigned int*)src,
            (__attribute__((address_space(3))) unsigned int*)((char*)plds + w * 1024),
            16, 0, 0);
        __builtin_amdgcn_global_load_lds(
            (const __attribute__((address_space(1))) unsigned int*)(src + 8192),
            (__attribute__((address_space(3))) unsigned int*)((char*)plds + 8192 + w * 1024),
            16, 0, 0);
    }
    __syncthreads();              // compiler drains vmcnt before barrier

    const f32x4 zero = {0.0f, 0.0f, 0.0f, 0.0f};

    // ---- row sweep: 8 iterations x 2 independent tiles (A and A+128 rows)
    const short8* xpA = reinterpret_cast<const short8*>(
        Xb + (h * 2048 + w * 16 + lm) * DIM + lk * 8);
    // psum layout: [block][row][2] f32; lanes l<32 store part lk.
    float* prow = psum + ((size_t)b * NROWS + h * 2048 + w * 16 + lm) * 2 + lk;
    const char* pl = (const char*)plds + l * 16;

    #pragma unroll 1
    for (int it = 0; it < 8; ++it) {
        short8 xA0 = xpA[0];
        short8 xA1 = xpA[4];          // +32 shorts (k 32..63)
        short8 xB0 = xpA[1024];       // +8192 shorts = +128 rows
        short8 xB1 = xpA[1028];

        float eA0 = 0.f, eA1 = 0.f, eA2 = 0.f, eA3 = 0.f;
        float eB0 = 0.f, eB1 = 0.f, eB2 = 0.f, eB3 = 0.f;
        #pragma unroll
        for (int ch = 0; ch < NCH; ++ch) {
            short8 p0 = *reinterpret_cast<const short8*>(pl + ch * 2048);
            short8 p1 = *reinterpret_cast<const short8*>(pl + ch * 2048 + 1024);
            f32x4 cA = __builtin_amdgcn_mfma_f32_16x16x32_bf16(p0, xA0, zero, 0, 0, 0);
            cA = __builtin_amdgcn_mfma_f32_16x16x32_bf16(p1, xA1, cA, 0, 0, 0);
            f32x4 cB = __builtin_amdgcn_mfma_f32_16x16x32_bf16(p0, xB0, zero, 0, 0, 0);
            cB = __builtin_amdgcn_mfma_f32_16x16x32_bf16(p1, xB1, cB, 0, 0, 0);
            eA0 += __builtin_amdgcn_exp2f(cA[0]);
            eA1 += __builtin_amdgcn_exp2f(cA[1]);
            eA2 += __builtin_amdgcn_exp2f(cA[2]);
            eA3 += __builtin_amdgcn_exp2f(cA[3]);
            eB0 += __builtin_amdgcn_exp2f(cB[0]);
            eB1 += __builtin_amdgcn_exp2f(cB[1]);
            eB2 += __builtin_amdgcn_exp2f(cB[2]);
            eB3 += __builtin_amdgcn_exp2f(cB[3]);
        }
        float sA = (eA0 + eA1) + (eA2 + eA3);
        float sB = (eB0 + eB1) + (eB2 + eB3);
        sA += __shfl_xor(sA, 32);     // lane holds partial over {lk, lk^2}
        sB += __shfl_xor(sB, 32);
        if (l < 32) {
            prow[0]       = sA;       // rows h*2048 + 256*it + w*16 .. +15
            prow[128 * 2] = sB;       // +128 rows
        }

        xpA += 2048;                  // +256 rows
        prow += 256 * 2;
    }
}

// ---- per-row finish + global mean, 256 blocks x 16 rows ------------------
// thread t: j = t>>4 sums block-range [j*32, +32); ri = t&15 = row in block.
__global__ void k_rowred(const float* __restrict__ psum, const float* __restrict__ st,
                         float* __restrict__ out) {
    __shared__ float red[256];
    __shared__ float rnll[16];
    int t  = threadIdx.x;
    int j  = t >> 4;
    int ri = t & 15;
    int r  = blockIdx.x * 16 + ri;
    const float2* p2 = reinterpret_cast<const float2*>(psum) + r;
    float s = 0.0f;
    #pragma unroll 4
    for (int i = j * 32; i < j * 32 + 32; ++i) {
        float2 v = p2[(size_t)i * NROWS];
        s += v.x + v.y;
    }
    red[t] = s;
    __syncthreads();
    if (t < 128) red[t] += red[t + 128];
    __syncthreads();
    if (t < 64)  red[t] += red[t + 64];
    __syncthreads();
    if (t < 32)  red[t] += red[t + 32];
    __syncthreads();
    if (t < 16) {
        float tot = red[t] + red[t + 16];
        rnll[t] = logf(tot) - st[r];
    }
    __syncthreads();
    if (t == 0) {
        float a = 0.0f;
        #pragma unroll
        for (int k = 0; k < 16; ++k) a += rnll[k];
        atomicAdd(out, a * (1.0f / (float)NROWS));
    }
}

extern "C" void kernel_launch(void* const* d_in, const int* in_sizes, int n_in,
                              void* d_out, int out_size, void* d_ws, size_t ws_size,
                              hipStream_t stream) {
    const float* X = (const float*)d_in[0];
    const float* P = (const float*)d_in[1];
    const int*   T = (const int*)  d_in[3];   // d_in[2] = indices (unused)
    float* out = (float*)d_out;

    char* ws = (char*)d_ws;
    unsigned short* Xb = (unsigned short*)ws;                 // 512 KB
    float* st   = (float*)(ws + (512 << 10));                 // 16 KB
    unsigned short* Pb = (unsigned short*)(ws + (576 << 10)); // 8 MB (packed frags)
    float* psum = (float*)(ws + (9 << 20));                   // 16 MB (512 x 4096 x 2)

    k_prep  <<<NPB + NROWS / 4, 256, 0, stream>>>(X, P, T, Pb, Xb, st, out);
    k_main  <<<NBLK * RSPLIT, 512, 0, stream>>>(Pb, Xb, psum);
    k_rowred<<<256, 256, 0, stream>>>(psum, st, out);
}